// Round 10
// baseline (213.758 us; speedup 1.0000x reference)
//
#include <hip/hip_runtime.h>
#include <hip/hip_bf16.h>

#define M_TOT 32768
#define DDIM  1024
#define ODIM  768
#define LN_EPS 1e-5f

typedef __attribute__((__ext_vector_type__(8))) short bf16x8;
typedef __attribute__((__ext_vector_type__(4))) float f32x4;

__device__ __forceinline__ unsigned short f2bf(float f) {
  union { __hip_bfloat16 h; unsigned short u; } cv;
  cv.h = __float2bfloat16(f);
  return cv.u;
}

__device__ __forceinline__ int pk2(float a, float b) {
  return (int)((unsigned)f2bf(a) | ((unsigned)f2bf(b) << 16));
}

__device__ __forceinline__ float silu_f(float v) {
  return v / (1.f + __expf(-v));
}

__global__ void wconv_kernel(const float4* __restrict__ Wf, ushort4* __restrict__ Wb, int n4) {
  int i = blockIdx.x * blockDim.x + threadIdx.x;
  if (i >= n4) return;
  float4 v = Wf[i];
  ushort4 o;
  o.x = f2bf(v.x); o.y = f2bf(v.y); o.z = f2bf(v.z); o.w = f2bf(v.w);
  Wb[i] = o;
}

// ====== fused LN+SiLU+GEMM+rearrange: R9 loop, reg-staged A from x ======
// BM=256, BN=192, BK=32; 512 thr = 8 waves (4M x 2N), wave C = 64x96.
// Ring-4 LDS (4 x 28 KB) + lnw/lnb fp32 tables (8 KB) + stats (2 KB).
// A-path: per K-tile, thread loads 2x8 fp32 of x (rows tid>>2 and +128,
// global chunk gc=tid&3), applies h=silu((x-mu)*r*w+b), packs bf16,
// ds_write_b128 to slot (row*4 + (gc ^ ((row>>1)&3))) -- identical LDS
// image to the old DMA path, so frag reads are untouched.
// vmcnt ledger (issue order per iter: x(t+2) then B(t+3)):
//   t==0: VMW(4)/(2);  1<=t<=29: VMW(2)/(1);  t>=30: VMW(0).
#define GBM 256
#define GBN 192
#define ABYTES 16384   // 256 rows x 64 B
#define BUFB   28672   // + 192 rows x 64 B
#define WL_OFF 114688
#define BL_OFF 118784
#define SM_OFF 122880
#define SR_OFF 123904

__device__ __forceinline__ void gload16(const void* g, void* l) {
  __builtin_amdgcn_global_load_lds(
      (const __attribute__((address_space(1))) unsigned int*)g,
      (__attribute__((address_space(3))) unsigned int*)l, 16, 0, 0);
}

#define VMW(n) asm volatile("s_waitcnt vmcnt(" #n ")" ::: "memory")

__global__ __launch_bounds__(512, 2)
void gemm_fused_kernel(const float* __restrict__ x,
                       const float* __restrict__ lnw,
                       const float* __restrict__ lnb,
                       const __hip_bfloat16* __restrict__ Wb,
                       const float* __restrict__ bias,
                       float* __restrict__ out)
{
  __shared__ char smem[124928];
  float* wLds  = (float*)(smem + WL_OFF);
  float* bLds  = (float*)(smem + BL_OFF);
  float* smean = (float*)(smem + SM_OFF);
  float* srstd = (float*)(smem + SR_OFF);

  const int tid  = threadIdx.x;
  const int lane = tid & 63;
  const int w    = tid >> 6;

  // bijective XCD swizzle (512 % 8 == 0); all 4 nt of an mt land on one XCD
  const int wg = blockIdx.x;
  const int sv = ((wg & 7) << 6) + (wg >> 3);
  const int mt = sv >> 2, nt = sv & 3;
  const int m0 = mt << 8, n0 = nt * GBN;

  // ---------- LN param preload + per-row stats (2 thr/row) ----------
  wLds[tid]       = lnw[tid];
  wLds[tid + 512] = lnw[tid + 512];
  bLds[tid]       = lnb[tid];
  bLds[tid + 512] = lnb[tid + 512];
  {
    const int srow = tid >> 1;
    const float4* xr = (const float4*)(x + (size_t)(m0 + srow) * DDIM) + ((tid & 1) << 7);
    float s0 = 0.f, s1 = 0.f, q0 = 0.f, q1 = 0.f;
#pragma unroll 4
    for (int j = 0; j < 128; j += 2) {
      float4 a = xr[j], b2 = xr[j + 1];
      s0 += a.x + a.y + a.z + a.w;
      q0 += a.x * a.x + a.y * a.y + a.z * a.z + a.w * a.w;
      s1 += b2.x + b2.y + b2.z + b2.w;
      q1 += b2.x * b2.x + b2.y * b2.y + b2.z * b2.z + b2.w * b2.w;
    }
    float s = s0 + s1, q = q0 + q1;
    s += __shfl_xor(s, 1);
    q += __shfl_xor(q, 1);
    if ((tid & 1) == 0) {
      float mean = s * (1.f / 1024.f);
      smean[srow] = mean;
      srstd[srow] = rsqrtf(q * (1.f / 1024.f) - mean * mean + LN_EPS);
    }
  }
  __syncthreads();

  // ---------- A ownership: rows tid>>2 and +128, chunk gc = tid&3 ----------
  const int row0 = tid >> 2;
  const int row1 = row0 + 128;
  const int gc   = tid & 3;
  const float mean0 = smean[row0], rstd0 = srstd[row0];
  const float mean1 = smean[row1], rstd1 = srstd[row1];
  const float* xr0 = x + (size_t)(m0 + row0) * DDIM + (gc << 3);
  const float* xr1 = x + (size_t)(m0 + row1) * DDIM + (gc << 3);
  const int aw0 = ((row0 << 2) + (gc ^ ((row0 >> 1) & 3))) << 4;
  const int aw1 = ((row1 << 2) + (gc ^ ((row1 >> 1) & 3))) << 4;

  // ---------- B staging (pre-swizzled source, as R9) ----------
  const bool roleB = (tid < 256);          // wave-uniform
  const __hip_bfloat16* bP0; int bD0;
  const __hip_bfloat16* bP1; int bD1;
  {
    int s = tid, row = s >> 2, chk = s & 3;
    bP0 = Wb + (size_t)(n0 + row) * DDIM + ((chk ^ ((row >> 1) & 3)) << 3);
    bD0 = ABYTES + (s << 4);
    int s2 = 512 + (tid & 255);
    int r2 = s2 >> 2, c2 = s2 & 3;
    bP1 = Wb + (size_t)(n0 + r2) * DDIM + ((c2 ^ ((r2 >> 1) & 3)) << 3);
    bD1 = ABYTES + (s2 << 4);
  }

  // ---------- MFMA fragment LDS read offsets (swizzle-matched) ----------
  const int wm = w >> 1, wn = w & 1;       // 4M x 2N
  const int lr = lane & 15, lq = lane >> 4;
  int aRd[4], bRd[6];
#pragma unroll
  for (int i = 0; i < 4; ++i) {
    int row = wm * 64 + i * 16 + lr;
    aRd[i] = row * 64 + ((lq ^ ((row >> 1) & 3)) << 4);
  }
#pragma unroll
  for (int j = 0; j < 6; ++j) {
    int row = wn * 96 + j * 16 + lr;
    bRd[j] = ABYTES + row * 64 + ((lq ^ ((row >> 1) & 3)) << 4);
  }

  float4 xa0, xa1, xb0, xb1;               // x regs for one K-tile

  auto xload = [&](int tt) {
    const int k0 = tt << 5;
    xa0 = *(const float4*)(xr0 + k0);
    xa1 = *(const float4*)(xr0 + k0 + 4);
    xb0 = *(const float4*)(xr1 + k0);
    xb1 = *(const float4*)(xr1 + k0 + 4);
  };
  auto aconv = [&](int tt) {               // LN+SiLU+pack+ds_write_b128 x2
    const float* wp = wLds + (tt << 5) + (gc << 3);
    const float* bp = bLds + (tt << 5) + (gc << 3);
    float4 w0 = *(const float4*)wp, w1 = *(const float4*)(wp + 4);
    float4 c0 = *(const float4*)bp, c1 = *(const float4*)(bp + 4);
    char* dst = smem + (tt & 3) * BUFB;
    {
      float h0 = silu_f((xa0.x - mean0) * rstd0 * w0.x + c0.x);
      float h1 = silu_f((xa0.y - mean0) * rstd0 * w0.y + c0.y);
      float h2 = silu_f((xa0.z - mean0) * rstd0 * w0.z + c0.z);
      float h3 = silu_f((xa0.w - mean0) * rstd0 * w0.w + c0.w);
      float h4 = silu_f((xa1.x - mean0) * rstd0 * w1.x + c1.x);
      float h5 = silu_f((xa1.y - mean0) * rstd0 * w1.y + c1.y);
      float h6 = silu_f((xa1.z - mean0) * rstd0 * w1.z + c1.z);
      float h7 = silu_f((xa1.w - mean0) * rstd0 * w1.w + c1.w);
      int4 v; v.x = pk2(h0, h1); v.y = pk2(h2, h3);
      v.z = pk2(h4, h5); v.w = pk2(h6, h7);
      *(int4*)(dst + aw0) = v;
    }
    {
      float h0 = silu_f((xb0.x - mean1) * rstd1 * w0.x + c0.x);
      float h1 = silu_f((xb0.y - mean1) * rstd1 * w0.y + c0.y);
      float h2 = silu_f((xb0.z - mean1) * rstd1 * w0.z + c0.z);
      float h3 = silu_f((xb0.w - mean1) * rstd1 * w0.w + c0.w);
      float h4 = silu_f((xb1.x - mean1) * rstd1 * w1.x + c1.x);
      float h5 = silu_f((xb1.y - mean1) * rstd1 * w1.y + c1.y);
      float h6 = silu_f((xb1.z - mean1) * rstd1 * w1.z + c1.z);
      float h7 = silu_f((xb1.w - mean1) * rstd1 * w1.w + c1.w);
      int4 v; v.x = pk2(h0, h1); v.y = pk2(h2, h3);
      v.z = pk2(h4, h5); v.w = pk2(h6, h7);
      *(int4*)(dst + aw1) = v;
    }
  };
  auto stageB = [&](int t) {               // 2 (waves 0-3) / 1 (waves 4-7)
    char* b = smem + (t & 3) * BUFB;
    const int k0 = t << 5;
    gload16(bP0 + k0, b + bD0);
    if (roleB) gload16(bP1 + k0, b + bD1);
  };

  f32x4 acc[4][6];
#pragma unroll
  for (int i = 0; i < 4; ++i)
#pragma unroll
    for (int j = 0; j < 6; ++j)
      acc[i][j] = (f32x4){0.f, 0.f, 0.f, 0.f};

  // ---------- prologue: A(0) in buf0, x(1) in regs, B(0..2) in flight ----
  xload(0);
  VMW(0);
  aconv(0);
  xload(1);
  stageB(0); stageB(1); stageB(2);
  asm volatile("s_waitcnt lgkmcnt(0)" ::: "memory");

  for (int t = 0; t < 32; ++t) {
    if (t == 0)       { if (roleB) VMW(4); else VMW(2); }
    else if (t <= 29) { if (roleB) VMW(2); else VMW(1); }
    else              { VMW(0); }
    __builtin_amdgcn_s_barrier();          // the ONLY barrier per K-tile
    asm volatile("" ::: "memory");

    const char* bb = smem + (t & 3) * BUFB;
    bf16x8 af[4], bf0[3], bf1[3];
#pragma unroll
    for (int i = 0; i < 4; ++i) af[i]  = *(const bf16x8*)(bb + aRd[i]);
#pragma unroll
    for (int j = 0; j < 3; ++j) bf0[j] = *(const bf16x8*)(bb + bRd[j]);

    if (t <= 30) aconv(t + 1);             // A(t+1) -> buf[(t+1)&3] (freed)
    if (t <= 29) xload(t + 2);             // overwrite x regs
    if (t <= 28) stageB(t + 3);            // buf[(t-1)&3] B-region (freed)

    __builtin_amdgcn_s_setprio(1);
#pragma unroll
    for (int i = 0; i < 4; ++i)
#pragma unroll
      for (int j = 0; j < 3; ++j)
        acc[i][j] = __builtin_amdgcn_mfma_f32_16x16x32_bf16(af[i], bf0[j], acc[i][j], 0, 0, 0);
    __builtin_amdgcn_s_setprio(0);

#pragma unroll
    for (int j = 0; j < 3; ++j) bf1[j] = *(const bf16x8*)(bb + bRd[3 + j]);

    __builtin_amdgcn_s_setprio(1);
#pragma unroll
    for (int i = 0; i < 4; ++i)
#pragma unroll
      for (int j = 0; j < 3; ++j)
        acc[i][3 + j] = __builtin_amdgcn_mfma_f32_16x16x32_bf16(af[i], bf1[j], acc[i][3 + j], 0, 0, 0);
    __builtin_amdgcn_s_setprio(0);

    asm volatile("s_waitcnt lgkmcnt(0)" ::: "memory");  // A-writes visible
  }

  // ---------- epilogue: 16 chunks of 16 tokens, coalesced f4 stores ----------
  const int b   = m0 >> 10;
  const int hl0 = (m0 & 1023) >> 5;
  float bv[6]; int cj[6], pwj[6], prj[6];
#pragma unroll
  for (int j = 0; j < 6; ++j) {
    int o = wn * 96 + j * 16 + lr;         // 0..191
    bv[j]  = bias[n0 + o];
    cj[j]  = o % 3;
    int oq = o / 3;
    pwj[j] = oq & 15;
    prj[j] = oq >> 4;                      // 0..3
  }
  float* ldsF = (float*)smem;

#pragma unroll
  for (int g = 0; g < 16; ++g) {
    if (wm == (g >> 2)) {
      const int i_f = g & 3;
#pragma unroll
      for (int j = 0; j < 6; ++j)
#pragma unroll
        for (int r = 0; r < 4; ++r) {
          const int tk = lq * 4 + r;
          ldsF[((cj[j] * 4 + prj[j]) << 8) + (tk << 4) + (pwj[j] ^ (lq << 2))] =
              acc[i_f][j][r] + bv[j];
        }
    }
    __syncthreads();
    const int hh = hl0 + (g >> 1);
#pragma unroll
    for (int u = 0; u < 2; ++u) {
      if (u == 1 && tid >= 256) break;     // 768 f4 total
      const int f   = (u << 9) + tid;
      const int c   = f >> 8;
      const int pr  = (f >> 6) & 3;
      const int tk  = (f >> 2) & 15;
      const int pw0 = (f & 3) << 2;
      const int lqw = tk >> 2;
      float4 v = *(const float4*)(ldsF + (((c * 4 + pr) << 8) + (tk << 4)
                                          + (pw0 ^ (lqw << 2))));
      const size_t idx = (((size_t)(b * 3 + c)) << 18)
                       + (size_t)((hh << 4) + (nt << 2) + pr) * 512
                       + ((g & 1) << 8) + (tk << 4) + pw0;
      *(float4*)(out + idx) = v;
    }
    __syncthreads();
  }
}

// ===================== fallback: fused (no workspace) =====================
#define BM 64
#define BK 32
#define NTHR 1024
#define LDS_BYTES 53760

__global__ __launch_bounds__(NTHR, 4)
void fused_kernel(const float* __restrict__ x,
                  const float* __restrict__ lnw,
                  const float* __restrict__ lnb,
                  const float* __restrict__ Wf,
                  const float* __restrict__ bias,
                  float* __restrict__ out)
{
  extern __shared__ char smem[];
  char* AsBase = smem;
  char* BsBase = smem + 4096;
  float* smean = (float*)(smem + 53248);
  float* srstd = smean + BM;

  const int tid = threadIdx.x;
  const int m0  = blockIdx.x * BM;
  const int bb   = m0 >> 10;
  const int h0   = (m0 & 1023) >> 5;

  {
    const int row = tid >> 4;
    const int sub = tid & 15;
    const float4* xr = (const float4*)(x + (size_t)(m0 + row) * DDIM);
    float s = 0.f, ss = 0.f;
#pragma unroll 4
    for (int j = 0; j < 16; ++j) {
      float4 v = xr[sub + (j << 4)];
      s  += v.x + v.y + v.z + v.w;
      ss += v.x * v.x + v.y * v.y + v.z * v.z + v.w * v.w;
    }
#pragma unroll
    for (int off = 1; off < 16; off <<= 1) {
      s  += __shfl_xor(s, off);
      ss += __shfl_xor(ss, off);
    }
    if (sub == 0) {
      float mean = s * (1.f / 1024.f);
      float var  = ss * (1.f / 1024.f) - mean * mean;
      smean[row] = mean;
      srstd[row] = rsqrtf(var + LN_EPS);
    }
  }
  __syncthreads();

  const int arow  = tid >> 4;
  const int acol2 = tid & 15;
  const int aOff  = (m0 + arow) * DDIM + (acol2 << 1);
  const int aDst  = (arow << 6) + ((((acol2 >> 2) ^ ((arow >> 2) & 3)) << 4)) + ((acol2 & 3) << 2);
  const float aMean = smean[arow];
  const float aRstd = srstd[arow];

  int bOffF[6], bDstF[6];
#pragma unroll
  for (int c = 0; c < 6; ++c) {
    int idx = tid + (c << 10);
    int r = idx >> 3, c4 = idx & 7;
    bOffF[c] = r * DDIM + (c4 << 2);
    bDstF[c] = (r << 6) + ((((c4 >> 1) ^ ((r >> 2) & 3)) << 4)) + ((c4 & 1) << 3);
  }

  const int lane = tid & 63;
  const int wid  = tid >> 6;
  const int lr   = lane & 15;
  const int lq   = lane >> 4;
  const int kswz = (lq ^ ((lr >> 2) & 3)) << 4;
  int aRd[4], bRd[3];
#pragma unroll
  for (int i = 0; i < 4; ++i) aRd[i] = (((i << 4) + lr) << 6) + kswz;
#pragma unroll
  for (int j = 0; j < 3; ++j) bRd[j] = ((wid * 48 + (j << 4) + lr) << 6) + kswz;

  float2 aReg, lwReg, lbReg;
  float4 bRegF[6];

  auto loadTile = [&](int tt) {
    const int k0 = tt * BK;
    aReg  = *(const float2*)(x + aOff + k0);
    lwReg = *(const float2*)(lnw + (acol2 << 1) + k0);
    lbReg = *(const float2*)(lnb + (acol2 << 1) + k0);
#pragma unroll
    for (int c = 0; c < 6; ++c)
      bRegF[c] = *(const float4*)(Wf + bOffF[c] + k0);
  };

  auto storeTile = [&]() {
    float hx = (aReg.x - aMean) * aRstd * lwReg.x + lbReg.x;
    float hy = (aReg.y - aMean) * aRstd * lwReg.y + lbReg.y;
    hx = silu_f(hx); hy = silu_f(hy);
    ushort2 ap; ap.x = f2bf(hx); ap.y = f2bf(hy);
    *(ushort2*)(AsBase + aDst) = ap;
#pragma unroll
    for (int c = 0; c < 6; ++c) {
      float4 wv = bRegF[c];
      ushort4 bp; bp.x = f2bf(wv.x); bp.y = f2bf(wv.y); bp.z = f2bf(wv.z); bp.w = f2bf(wv.w);
      *(ushort4*)(BsBase + bDstF[c]) = bp;
    }
  };

  f32x4 acc[4][3];
#pragma unroll
  for (int i = 0; i < 4; ++i)
#pragma unroll
    for (int j = 0; j < 3; ++j)
      acc[i][j] = (f32x4){0.f, 0.f, 0.f, 0.f};

  loadTile(0);
  storeTile();
  __syncthreads();

  for (int t = 0; t < 32; ++t) {
    if (t < 31) loadTile(t + 1);
    bf16x8 af[4], bfr[3];
#pragma unroll
    for (int i = 0; i < 4; ++i) af[i] = *(const bf16x8*)(AsBase + aRd[i]);
#pragma unroll
    for (int j = 0; j < 3; ++j) bfr[j] = *(const bf16x8*)(BsBase + bRd[j]);
#pragma unroll
    for (int i = 0; i < 4; ++i)
#pragma unroll
      for (int j = 0; j < 3; ++j)
        acc[i][j] = __builtin_amdgcn_mfma_f32_16x16x32_bf16(af[i], bfr[j], acc[i][j], 0, 0, 0);
    __syncthreads();
    if (t < 31) storeTile();
    __syncthreads();
  }

  float* ldsF = (float*)smem;
  float bv[3]; int cv[3], phv[3], pwv[3];
#pragma unroll
  for (int j = 0; j < 3; ++j) {
    const int o = wid * 48 + (j << 4) + lr;
    bv[j]  = bias[o];
    cv[j]  = o % 3;
    const int oq = o / 3;
    pwv[j] = oq & 15;
    phv[j] = oq >> 4;
  }

#pragma unroll
  for (int i = 0; i < 4; ++i) {
#pragma unroll
    for (int j = 0; j < 3; ++j) {
#pragma unroll
      for (int r = 0; r < 4; ++r) {
        const int wl  = (lq << 2) + r;
        const int lin = ((cv[j] * 16 + phv[j]) << 8) + (wl << 4) + pwv[j];
        const int dws = lin ^ (cv[j] << 2) ^ (((lin >> 6) & 1) << 4);
        ldsF[dws] = acc[i][j][r] + bv[j];
      }
    }
    __syncthreads();
    const int hq = h0 + (i >> 1);
    const int w0 = (i & 1) << 4;
#pragma unroll
    for (int q = 0; q < 3; ++q) {
      const int g4  = (q << 10) + tid;
      const int dw  = g4 << 2;
      const int run = dw >> 8;
      const int c   = run >> 4;
      const int ph  = run & 15;
      const int wl  = (dw >> 4) & 15;
      const int pw  = dw & 15;
      const int dws = dw ^ (c << 2) ^ (((dw >> 6) & 1) << 4);
      float4 v = *(const float4*)(ldsF + dws);
      const size_t idx = (((size_t)(bb * 3 + c)) << 18)
                       + ((size_t)((hq << 4) + ph) << 9)
                       + ((w0 + wl) << 4) + pw;
      *(float4*)(out + idx) = v;
    }
    __syncthreads();
  }
}

extern "C" void kernel_launch(void* const* d_in, const int* in_sizes, int n_in,
                              void* d_out, int out_size, void* d_ws, size_t ws_size,
                              hipStream_t stream) {
  const float* x    = (const float*)d_in[0];
  const float* lnw  = (const float*)d_in[1];
  const float* lnb  = (const float*)d_in[2];
  const float* W    = (const float*)d_in[3];
  const float* bias = (const float*)d_in[4];
  float* out = (float*)d_out;

  const size_t wbBytes = (size_t)ODIM * DDIM * sizeof(__hip_bfloat16);   // 1.5 MB
  __hip_bfloat16* Wb = (__hip_bfloat16*)d_ws;

  if (ws_size >= wbBytes) {
    wconv_kernel<<<dim3(768), dim3(256), 0, stream>>>((const float4*)W, (ushort4*)Wb,
                                                      ODIM * DDIM / 4);
    gemm_fused_kernel<<<dim3((M_TOT / GBM) * (ODIM / GBN)), dim3(512), 0, stream>>>(
        x, lnw, lnb, Wb, bias, out);
  } else {
    fused_kernel<<<dim3(M_TOT / BM), dim3(NTHR), LDS_BYTES, stream>>>(
        x, lnw, lnb, W, bias, out);
  }
}

// Round 11
// 100.885 us; speedup vs baseline: 2.1188x; 2.1188x over previous
//
#include <hip/hip_runtime.h>
#include <hip/hip_bf16.h>

#define M_TOT 32768
#define DDIM  1024
#define ODIM  768
#define LN_EPS 1e-5f

typedef __attribute__((__ext_vector_type__(8))) short bf16x8;
typedef __attribute__((__ext_vector_type__(4))) float f32x4;

__device__ __forceinline__ unsigned short f2bf(float f) {
  union { __hip_bfloat16 h; unsigned short u; } cv;
  cv.h = __float2bfloat16(f);
  return cv.u;
}

__device__ __forceinline__ float silu_f(float v) {
  return v / (1.f + __expf(-v));
}

__global__ void wconv_kernel(const float4* __restrict__ Wf, ushort4* __restrict__ Wb, int n4) {
  int i = blockIdx.x * blockDim.x + threadIdx.x;
  if (i >= n4) return;
  float4 v = Wf[i];
  ushort4 o;
  o.x = f2bf(v.x); o.y = f2bf(v.y); o.z = f2bf(v.z); o.w = f2bf(v.w);
  Wb[i] = o;
}

// ===================== kernel 1: LN + SiLU -> h (bf16) =====================
__global__ __launch_bounds__(256)
void ln_silu_kernel(const float* __restrict__ x, const float* __restrict__ lnw,
                    const float* __restrict__ lnb, __hip_bfloat16* __restrict__ h)
{
  const int tid  = threadIdx.x;
  const int lane = tid & 63;
  const int wid  = tid >> 6;
  const int row  = blockIdx.x * 4 + wid;

  const float4* xr = (const float4*)(x + (size_t)row * DDIM);
  float4 v[4];
#pragma unroll
  for (int jj = 0; jj < 4; ++jj) v[jj] = xr[lane + 64 * jj];

  float s = 0.f, ss = 0.f;
#pragma unroll
  for (int jj = 0; jj < 4; ++jj) {
    float4 a = v[jj];
    s  += a.x + a.y + a.z + a.w;
    ss += a.x * a.x + a.y * a.y + a.z * a.z + a.w * a.w;
  }
#pragma unroll
  for (int off = 1; off < 64; off <<= 1) {
    s  += __shfl_xor(s, off);
    ss += __shfl_xor(ss, off);
  }
  const float mean = s * (1.f / 1024.f);
  const float rstd = rsqrtf(ss * (1.f / 1024.f) - mean * mean + LN_EPS);

  ushort4* hr = (ushort4*)(h + (size_t)row * DDIM);
#pragma unroll
  for (int jj = 0; jj < 4; ++jj) {
    float4 wv = ((const float4*)lnw)[lane + 64 * jj];
    float4 bv = ((const float4*)lnb)[lane + 64 * jj];
    float4 a  = v[jj];
    float e0 = silu_f((a.x - mean) * rstd * wv.x + bv.x);
    float e1 = silu_f((a.y - mean) * rstd * wv.y + bv.y);
    float e2 = silu_f((a.z - mean) * rstd * wv.z + bv.z);
    float e3 = silu_f((a.w - mean) * rstd * wv.w + bv.w);
    ushort4 o; o.x = f2bf(e0); o.y = f2bf(e1); o.z = f2bf(e2); o.w = f2bf(e3);
    hr[lane + 64 * jj] = o;
  }
}

// ============ kernel 2: GEMM + rearrange, BK=64 ring-2, 1 barrier/tile ======
// BM=256, BN=192, BK=64; 512 thr = 8 waves (4M x 2N), wave C = 64x96.
// Ring-2 LDS (2 x 56 KB static = 114688). 16 K-tiles (half the sync events
// of the BK=32 variants -- that amortization is this round's single change).
// Per tile: VMW(0) [stage(t) landed; stage(t+1) had ~full tile-t compute to
// land, so drain ~free] -> barrier -> free-run {48 MFMA in 2 k-halves,
// compiler-emitted lgkmcnt} ; stage(t+1) issued right after the barrier.
// Rows = 128 B -> swizzle chunk ^= (row & 7): each 16-lane b128 phase hits
// every 16-B slot exactly 2x = conflict-free (m136: 2-way free).
#define GBM 256
#define GBN 192
#define GBK 64
#define ABY  32768   // 256 rows x 128 B
#define BUFB 57344   // + 192 rows x 128 B

__device__ __forceinline__ void gload16(const void* g, void* l) {
  __builtin_amdgcn_global_load_lds(
      (const __attribute__((address_space(1))) unsigned int*)g,
      (__attribute__((address_space(3))) unsigned int*)l, 16, 0, 0);
}

#define VMW(n) asm volatile("s_waitcnt vmcnt(" #n ")" ::: "memory")

__global__ __launch_bounds__(512, 2)
void gemm_kernel(const __hip_bfloat16* __restrict__ h,
                 const __hip_bfloat16* __restrict__ Wb,
                 const float* __restrict__ bias,
                 float* __restrict__ out)
{
  __shared__ char smem[2 * BUFB];          // 114688 B static
  const int tid  = threadIdx.x;
  const int lane = tid & 63;
  const int w    = tid >> 6;

  // bijective XCD swizzle (512 % 8 == 0); nt fastest -> same-XCD shares A
  const int wg = blockIdx.x;
  const int sv = ((wg & 7) << 6) + (wg >> 3);
  const int mt = sv >> 2, nt = sv & 3;
  const int m0 = mt << 8, n0 = nt * GBN;

  // ---- staging sources (pre-swizzled: 16B chunk ^= row&7; 8 chunks/row) ----
  // A: 2048 slots -> 4/thread; B: 1536 slots -> 3/thread.
  const __hip_bfloat16* aP[4]; int aD[4];
#pragma unroll
  for (int q = 0; q < 4; ++q) {
    int s = (q << 9) + tid;
    int row = s >> 3, chk = s & 7;
    aP[q] = h + (size_t)(m0 + row) * DDIM + ((chk ^ (row & 7)) << 3);
    aD[q] = s << 4;
  }
  const __hip_bfloat16* bP[3]; int bD[3];
#pragma unroll
  for (int q = 0; q < 3; ++q) {
    int s = (q << 9) + tid;
    int row = s >> 3, chk = s & 7;
    bP[q] = Wb + (size_t)(n0 + row) * DDIM + ((chk ^ (row & 7)) << 3);
    bD[q] = ABY + (s << 4);
  }

  // ---- MFMA fragment LDS read offsets (swizzle-matched) ----
  const int wm = w >> 1, wn = w & 1;       // 4M x 2N
  const int lr = lane & 15, lq = lane >> 4;
  int aRd[8], bRd[12];                     // [kk*4+i], [kk*6+j]
#pragma unroll
  for (int kk = 0; kk < 2; ++kk) {
#pragma unroll
    for (int i = 0; i < 4; ++i) {
      int row = wm * 64 + i * 16 + lr;
      aRd[kk * 4 + i] = row * 128 + ((((kk << 2) | lq) ^ (row & 7)) << 4);
    }
#pragma unroll
    for (int j = 0; j < 6; ++j) {
      int row = wn * 96 + j * 16 + lr;
      bRd[kk * 6 + j] = ABY + row * 128 + ((((kk << 2) | lq) ^ (row & 7)) << 4);
    }
  }

  auto stage = [&](int t) {                // 7 loads/thread
    char* b = smem + (t & 1) * BUFB;
    const int k0 = t << 6;
#pragma unroll
    for (int q = 0; q < 4; ++q) gload16(aP[q] + k0, b + aD[q]);
#pragma unroll
    for (int q = 0; q < 3; ++q) gload16(bP[q] + k0, b + bD[q]);
  };

  f32x4 acc[4][6];
#pragma unroll
  for (int i = 0; i < 4; ++i)
#pragma unroll
    for (int j = 0; j < 6; ++j)
      acc[i][j] = (f32x4){0.f, 0.f, 0.f, 0.f};

  stage(0);

  for (int t = 0; t < 16; ++t) {
    VMW(0);                                // stage(t) landed (covered by
    __builtin_amdgcn_s_barrier();          //   tile t-1's compute)
    asm volatile("" ::: "memory");

    const char* bb = smem + (t & 1) * BUFB;
    if (t < 15) stage(t + 1);              // into other buffer; reads of it
                                           // retired before top barrier
    bf16x8 af[4], bfq[6];
    // ---- k-half 0: 24 MFMA ----
#pragma unroll
    for (int i = 0; i < 4; ++i) af[i]  = *(const bf16x8*)(bb + aRd[i]);
#pragma unroll
    for (int j = 0; j < 6; ++j) bfq[j] = *(const bf16x8*)(bb + bRd[j]);
    __builtin_amdgcn_s_setprio(1);
#pragma unroll
    for (int i = 0; i < 4; ++i)
#pragma unroll
      for (int j = 0; j < 6; ++j)
        acc[i][j] = __builtin_amdgcn_mfma_f32_16x16x32_bf16(af[i], bfq[j], acc[i][j], 0, 0, 0);
    __builtin_amdgcn_s_setprio(0);
    // ---- k-half 1: 24 MFMA ----
#pragma unroll
    for (int i = 0; i < 4; ++i) af[i]  = *(const bf16x8*)(bb + aRd[4 + i]);
#pragma unroll
    for (int j = 0; j < 6; ++j) bfq[j] = *(const bf16x8*)(bb + bRd[6 + j]);
    __builtin_amdgcn_s_setprio(1);
#pragma unroll
    for (int i = 0; i < 4; ++i)
#pragma unroll
      for (int j = 0; j < 6; ++j)
        acc[i][j] = __builtin_amdgcn_mfma_f32_16x16x32_bf16(af[i], bfq[j], acc[i][j], 0, 0, 0);
    __builtin_amdgcn_s_setprio(0);
  }

  // ---------- epilogue: 16 chunks of 16 tokens, coalesced f4 stores ----------
  const int b   = m0 >> 10;
  const int hl0 = (m0 & 1023) >> 5;
  float bv[6]; int cj[6], pwj[6], prj[6];
#pragma unroll
  for (int j = 0; j < 6; ++j) {
    int o = wn * 96 + j * 16 + lr;         // 0..191
    bv[j]  = bias[n0 + o];
    cj[j]  = o % 3;
    int oq = o / 3;
    pwj[j] = oq & 15;
    prj[j] = oq >> 4;                      // 0..3
  }
  float* ldsF = (float*)smem;

#pragma unroll
  for (int g = 0; g < 16; ++g) {
    if (wm == (g >> 2)) {
      const int i_f = g & 3;
#pragma unroll
      for (int j = 0; j < 6; ++j)
#pragma unroll
        for (int r = 0; r < 4; ++r) {
          const int tk = lq * 4 + r;
          ldsF[((cj[j] * 4 + prj[j]) << 8) + (tk << 4) + (pwj[j] ^ (lq << 2))] =
              acc[i_f][j][r] + bv[j];
        }
    }
    __syncthreads();
    const int hh = hl0 + (g >> 1);
#pragma unroll
    for (int u = 0; u < 2; ++u) {
      if (u == 1 && tid >= 256) break;     // 768 f4 total
      const int f   = (u << 9) + tid;
      const int c   = f >> 8;
      const int pr  = (f >> 6) & 3;
      const int tk  = (f >> 2) & 15;
      const int pw0 = (f & 3) << 2;
      const int lqw = tk >> 2;
      float4 v = *(const float4*)(ldsF + (((c * 4 + pr) << 8) + (tk << 4)
                                          + (pw0 ^ (lqw << 2))));
      const size_t idx = (((size_t)(b * 3 + c)) << 18)
                       + (size_t)((hh << 4) + (nt << 2) + pr) * 512
                       + ((g & 1) << 8) + (tk << 4) + pw0;
      *(float4*)(out + idx) = v;
    }
    __syncthreads();
  }
}

// ===================== fallback: fused (no workspace) =====================
#define BM 64
#define BK 32
#define NTHR 1024
#define LDS_BYTES 53760

__global__ __launch_bounds__(NTHR, 4)
void fused_kernel(const float* __restrict__ x,
                  const float* __restrict__ lnw,
                  const float* __restrict__ lnb,
                  const float* __restrict__ Wf,
                  const float* __restrict__ bias,
                  float* __restrict__ out)
{
  extern __shared__ char smem[];
  char* AsBase = smem;
  char* BsBase = smem + 4096;
  float* smean = (float*)(smem + 53248);
  float* srstd = smean + BM;

  const int tid = threadIdx.x;
  const int m0  = blockIdx.x * BM;
  const int bb   = m0 >> 10;
  const int h0   = (m0 & 1023) >> 5;

  {
    const int row = tid >> 4;
    const int sub = tid & 15;
    const float4* xr = (const float4*)(x + (size_t)(m0 + row) * DDIM);
    float s = 0.f, ss = 0.f;
#pragma unroll 4
    for (int j = 0; j < 16; ++j) {
      float4 v = xr[sub + (j << 4)];
      s  += v.x + v.y + v.z + v.w;
      ss += v.x * v.x + v.y * v.y + v.z * v.z + v.w * v.w;
    }
#pragma unroll
    for (int off = 1; off < 16; off <<= 1) {
      s  += __shfl_xor(s, off);
      ss += __shfl_xor(ss, off);
    }
    if (sub == 0) {
      float mean = s * (1.f / 1024.f);
      float var  = ss * (1.f / 1024.f) - mean * mean;
      smean[row] = mean;
      srstd[row] = rsqrtf(var + LN_EPS);
    }
  }
  __syncthreads();

  const int arow  = tid >> 4;
  const int acol2 = tid & 15;
  const int aOff  = (m0 + arow) * DDIM + (acol2 << 1);
  const int aDst  = (arow << 6) + ((((acol2 >> 2) ^ ((arow >> 2) & 3)) << 4)) + ((acol2 & 3) << 2);
  const float aMean = smean[arow];
  const float aRstd = srstd[arow];

  int bOffF[6], bDstF[6];
#pragma unroll
  for (int c = 0; c < 6; ++c) {
    int idx = tid + (c << 10);
    int r = idx >> 3, c4 = idx & 7;
    bOffF[c] = r * DDIM + (c4 << 2);
    bDstF[c] = (r << 6) + ((((c4 >> 1) ^ ((r >> 2) & 3)) << 4)) + ((c4 & 1) << 3);
  }

  const int lane = tid & 63;
  const int wid  = tid >> 6;
  const int lr   = lane & 15;
  const int lq   = lane >> 4;
  const int kswz = (lq ^ ((lr >> 2) & 3)) << 4;
  int aRd[4], bRd[3];
#pragma unroll
  for (int i = 0; i < 4; ++i) aRd[i] = (((i << 4) + lr) << 6) + kswz;
#pragma unroll
  for (int j = 0; j < 3; ++j) bRd[j] = ((wid * 48 + (j << 4) + lr) << 6) + kswz;

  float2 aReg, lwReg, lbReg;
  float4 bRegF[6];

  auto loadTile = [&](int tt) {
    const int k0 = tt * BK;
    aReg  = *(const float2*)(x + aOff + k0);
    lwReg = *(const float2*)(lnw + (acol2 << 1) + k0);
    lbReg = *(const float2*)(lnb + (acol2 << 1) + k0);
#pragma unroll
    for (int c = 0; c < 6; ++c)
      bRegF[c] = *(const float4*)(Wf + bOffF[c] + k0);
  };

  auto storeTile = [&]() {
    float hx = (aReg.x - aMean) * aRstd * lwReg.x + lbReg.x;
    float hy = (aReg.y - aMean) * aRstd * lwReg.y + lbReg.y;
    hx = silu_f(hx); hy = silu_f(hy);
    ushort2 ap; ap.x = f2bf(hx); ap.y = f2bf(hy);
    *(ushort2*)(AsBase + aDst) = ap;
#pragma unroll
    for (int c = 0; c < 6; ++c) {
      float4 wv = bRegF[c];
      ushort4 bp; bp.x = f2bf(wv.x); bp.y = f2bf(wv.y); bp.z = f2bf(wv.z); bp.w = f2bf(wv.w);
      *(ushort4*)(BsBase + bDstF[c]) = bp;
    }
  };

  f32x4 acc[4][3];
#pragma unroll
  for (int i = 0; i < 4; ++i)
#pragma unroll
    for (int j = 0; j < 3; ++j)
      acc[i][j] = (f32x4){0.f, 0.f, 0.f, 0.f};

  loadTile(0);
  storeTile();
  __syncthreads();

  for (int t = 0; t < 32; ++t) {
    if (t < 31) loadTile(t + 1);
    bf16x8 af[4], bfr[3];
#pragma unroll
    for (int i = 0; i < 4; ++i) af[i] = *(const bf16x8*)(AsBase + aRd[i]);
#pragma unroll
    for (int j = 0; j < 3; ++j) bfr[j] = *(const bf16x8*)(BsBase + bRd[j]);
#pragma unroll
    for (int i = 0; i < 4; ++i)
#pragma unroll
      for (int j = 0; j < 3; ++j)
        acc[i][j] = __builtin_amdgcn_mfma_f32_16x16x32_bf16(af[i], bfr[j], acc[i][j], 0, 0, 0);
    __syncthreads();
    if (t < 31) storeTile();
    __syncthreads();
  }

  float* ldsF = (float*)smem;
  float bv[3]; int cv[3], phv[3], pwv[3];
#pragma unroll
  for (int j = 0; j < 3; ++j) {
    const int o = wid * 48 + (j << 4) + lr;
    bv[j]  = bias[o];
    cv[j]  = o % 3;
    const int oq = o / 3;
    pwv[j] = oq & 15;
    phv[j] = oq >> 4;
  }

#pragma unroll
  for (int i = 0; i < 4; ++i) {
#pragma unroll
    for (int j = 0; j < 3; ++j) {
#pragma unroll
      for (int r = 0; r < 4; ++r) {
        const int wl  = (lq << 2) + r;
        const int lin = ((cv[j] * 16 + phv[j]) << 8) + (wl << 4) + pwv[j];
        const int dws = lin ^ (cv[j] << 2) ^ (((lin >> 6) & 1) << 4);
        ldsF[dws] = acc[i][j][r] + bv[j];
      }
    }
    __syncthreads();
    const int hq = h0 + (i >> 1);
    const int w0 = (i & 1) << 4;
#pragma unroll
    for (int q = 0; q < 3; ++q) {
      const int g4  = (q << 10) + tid;
      const int dw  = g4 << 2;
      const int run = dw >> 8;
      const int c   = run >> 4;
      const int ph  = run & 15;
      const int wl  = (dw >> 4) & 15;
      const int pw  = dw & 15;
      const int dws = dw ^ (c << 2) ^ (((dw >> 6) & 1) << 4);
      float4 v = *(const float4*)(ldsF + dws);
      const size_t idx = (((size_t)(bb * 3 + c)) << 18)
                       + ((size_t)((hq << 4) + ph) << 9)
                       + ((w0 + wl) << 4) + pw;
      *(float4*)(out + idx) = v;
    }
    __syncthreads();
  }
}

extern "C" void kernel_launch(void* const* d_in, const int* in_sizes, int n_in,
                              void* d_out, int out_size, void* d_ws, size_t ws_size,
                              hipStream_t stream) {
  const float* x    = (const float*)d_in[0];
  const float* lnw  = (const float*)d_in[1];
  const float* lnb  = (const float*)d_in[2];
  const float* W    = (const float*)d_in[3];
  const float* bias = (const float*)d_in[4];
  float* out = (float*)d_out;

  const size_t wbBytes = (size_t)ODIM * DDIM * sizeof(__hip_bfloat16);   // 1.5 MB
  const size_t hBytes  = (size_t)M_TOT * DDIM * sizeof(__hip_bfloat16);  // 64 MB
  __hip_bfloat16* Wb = (__hip_bfloat16*)d_ws;
  __hip_bfloat16* hb = (__hip_bfloat16*)((char*)d_ws + wbBytes);

  if (ws_size >= wbBytes + hBytes) {
    wconv_kernel<<<dim3(768), dim3(256), 0, stream>>>((const float4*)W, (ushort4*)Wb,
                                                      ODIM * DDIM / 4);
    ln_silu_kernel<<<dim3(M_TOT / 4), dim3(256), 0, stream>>>(x, lnw, lnb, hb);
    gemm_kernel<<<dim3((M_TOT / GBM) * (ODIM / GBN)), dim3(512), 0, stream>>>(hb, Wb, bias, out);
  } else {
    fused_kernel<<<dim3(M_TOT / BM), dim3(NTHR), LDS_BYTES, stream>>>(
        x, lnw, lnb, W, bias, out);
  }
}

// Round 12
// 100.237 us; speedup vs baseline: 2.1325x; 1.0065x over previous
//
#include <hip/hip_runtime.h>
#include <hip/hip_bf16.h>

#define M_TOT 32768
#define DDIM  1024
#define ODIM  768
#define LN_EPS 1e-5f

typedef __attribute__((__ext_vector_type__(8))) short bf16x8;
typedef __attribute__((__ext_vector_type__(4))) float f32x4;

__device__ __forceinline__ unsigned short f2bf(float f) {
  union { __hip_bfloat16 h; unsigned short u; } cv;
  cv.h = __float2bfloat16(f);
  return cv.u;
}

__device__ __forceinline__ float silu_f(float v) {
  return v / (1.f + __expf(-v));
}

__global__ void wconv_kernel(const float4* __restrict__ Wf, ushort4* __restrict__ Wb, int n4) {
  int i = blockIdx.x * blockDim.x + threadIdx.x;
  if (i >= n4) return;
  float4 v = Wf[i];
  ushort4 o;
  o.x = f2bf(v.x); o.y = f2bf(v.y); o.z = f2bf(v.z); o.w = f2bf(v.w);
  Wb[i] = o;
}

// ===================== kernel 1: LN + SiLU -> h (bf16) =====================
__global__ __launch_bounds__(256)
void ln_silu_kernel(const float* __restrict__ x, const float* __restrict__ lnw,
                    const float* __restrict__ lnb, __hip_bfloat16* __restrict__ h)
{
  const int tid  = threadIdx.x;
  const int lane = tid & 63;
  const int wid  = tid >> 6;
  const int row  = blockIdx.x * 4 + wid;

  const float4* xr = (const float4*)(x + (size_t)row * DDIM);
  float4 v[4];
#pragma unroll
  for (int jj = 0; jj < 4; ++jj) v[jj] = xr[lane + 64 * jj];

  float s = 0.f, ss = 0.f;
#pragma unroll
  for (int jj = 0; jj < 4; ++jj) {
    float4 a = v[jj];
    s  += a.x + a.y + a.z + a.w;
    ss += a.x * a.x + a.y * a.y + a.z * a.z + a.w * a.w;
  }
#pragma unroll
  for (int off = 1; off < 64; off <<= 1) {
    s  += __shfl_xor(s, off);
    ss += __shfl_xor(ss, off);
  }
  const float mean = s * (1.f / 1024.f);
  const float rstd = rsqrtf(ss * (1.f / 1024.f) - mean * mean + LN_EPS);

  ushort4* hr = (ushort4*)(h + (size_t)row * DDIM);
#pragma unroll
  for (int jj = 0; jj < 4; ++jj) {
    float4 wv = ((const float4*)lnw)[lane + 64 * jj];
    float4 bv = ((const float4*)lnb)[lane + 64 * jj];
    float4 a  = v[jj];
    float e0 = silu_f((a.x - mean) * rstd * wv.x + bv.x);
    float e1 = silu_f((a.y - mean) * rstd * wv.y + bv.y);
    float e2 = silu_f((a.z - mean) * rstd * wv.z + bv.z);
    float e3 = silu_f((a.w - mean) * rstd * wv.w + bv.w);
    ushort4 o; o.x = f2bf(e0); o.y = f2bf(e1); o.z = f2bf(e2); o.w = f2bf(e3);
    hr[lane + 64 * jj] = o;
  }
}

// ==== kernel 2: GEMM + rearrange, BK=64 ring-2, 2 BLOCKS/CU RESIDENT =======
// BM=128, BN=192, BK=64; 256 thr = 4 waves (2M x 2N), wave C = 64x96
// (per-wave tile/acc identical to R11 -- only block size halved).
// Ring-2 LDS = 2 x 40960 = 81920 B -> exactly 2 blocks per 160 KiB CU.
// Rationale: R11 (112 KB, 1 block/CU) measured ~5000 cyc/tile vs ~1860 MFMA
// + ~1730 LDS floors -- 60% stall with nothing co-resident to fill it.
// Two resident blocks at independent phases give the m114 cross-wave
// overlap (one block's MFMA fills the other's vmcnt drain).
// Schedule per tile (unchanged from R11): VMW(0) -> barrier -> stage(t+1)
// -> free-run {frag ds_reads, 48 MFMA} with compiler lgkmcnt; setprio on
// MFMA clusters. Swizzle: 16B chunk ^= row&7 (128 B rows, conflict-free).
#define GBM 128
#define GBN 192
#define GBK 64
#define ABY  16384   // 128 rows x 128 B
#define BUFB 40960   // + 192 rows x 128 B

__device__ __forceinline__ void gload16(const void* g, void* l) {
  __builtin_amdgcn_global_load_lds(
      (const __attribute__((address_space(1))) unsigned int*)g,
      (__attribute__((address_space(3))) unsigned int*)l, 16, 0, 0);
}

#define VMW(n) asm volatile("s_waitcnt vmcnt(" #n ")" ::: "memory")

__global__ __launch_bounds__(256, 2)
void gemm_kernel(const __hip_bfloat16* __restrict__ h,
                 const __hip_bfloat16* __restrict__ Wb,
                 const float* __restrict__ bias,
                 float* __restrict__ out)
{
  __shared__ char smem[2 * BUFB];          // 81920 B static
  const int tid  = threadIdx.x;
  const int lane = tid & 63;
  const int w    = tid >> 6;

  // bijective XCD swizzle (1024 % 8 == 0); nt fastest -> same-XCD shares A
  const int wg = blockIdx.x;
  const int sv = ((wg & 7) << 7) + (wg >> 3);
  const int mt = sv >> 2, nt = sv & 3;
  const int m0 = mt << 7, n0 = nt * GBN;

  // ---- staging sources (pre-swizzled: 16B chunk ^= row&7; 8 chunks/row) ----
  // A: 1024 slots -> 4/thread; B: 1536 slots -> 6/thread.
  const __hip_bfloat16* aP[4]; int aD[4];
#pragma unroll
  for (int q = 0; q < 4; ++q) {
    int s = (q << 8) + tid;
    int row = s >> 3, chk = s & 7;
    aP[q] = h + (size_t)(m0 + row) * DDIM + ((chk ^ (row & 7)) << 3);
    aD[q] = s << 4;
  }
  const __hip_bfloat16* bP[6]; int bD[6];
#pragma unroll
  for (int q = 0; q < 6; ++q) {
    int s = (q << 8) + tid;
    int row = s >> 3, chk = s & 7;
    bP[q] = Wb + (size_t)(n0 + row) * DDIM + ((chk ^ (row & 7)) << 3);
    bD[q] = ABY + (s << 4);
  }

  // ---- MFMA fragment LDS read offsets (swizzle-matched) ----
  const int wm = w >> 1, wn = w & 1;       // 2M x 2N
  const int lr = lane & 15, lq = lane >> 4;
  int aRd[8], bRd[12];                     // [kk*4+i], [kk*6+j]
#pragma unroll
  for (int kk = 0; kk < 2; ++kk) {
#pragma unroll
    for (int i = 0; i < 4; ++i) {
      int row = wm * 64 + i * 16 + lr;
      aRd[kk * 4 + i] = row * 128 + ((((kk << 2) | lq) ^ (row & 7)) << 4);
    }
#pragma unroll
    for (int j = 0; j < 6; ++j) {
      int row = wn * 96 + j * 16 + lr;
      bRd[kk * 6 + j] = ABY + row * 128 + ((((kk << 2) | lq) ^ (row & 7)) << 4);
    }
  }

  auto stage = [&](int t) {                // 10 loads/thread
    char* b = smem + (t & 1) * BUFB;
    const int k0 = t << 6;
#pragma unroll
    for (int q = 0; q < 4; ++q) gload16(aP[q] + k0, b + aD[q]);
#pragma unroll
    for (int q = 0; q < 6; ++q) gload16(bP[q] + k0, b + bD[q]);
  };

  f32x4 acc[4][6];
#pragma unroll
  for (int i = 0; i < 4; ++i)
#pragma unroll
    for (int j = 0; j < 6; ++j)
      acc[i][j] = (f32x4){0.f, 0.f, 0.f, 0.f};

  stage(0);

  for (int t = 0; t < 16; ++t) {
    VMW(0);                                // stage(t) landed (drain overlaps
    __builtin_amdgcn_s_barrier();          //   the co-resident block's work)
    asm volatile("" ::: "memory");

    const char* bb = smem + (t & 1) * BUFB;
    if (t < 15) stage(t + 1);              // other buffer; its readers retired
                                           // before they crossed the barrier
    bf16x8 af[4], bfq[6];
    // ---- k-half 0: 24 MFMA ----
#pragma unroll
    for (int i = 0; i < 4; ++i) af[i]  = *(const bf16x8*)(bb + aRd[i]);
#pragma unroll
    for (int j = 0; j < 6; ++j) bfq[j] = *(const bf16x8*)(bb + bRd[j]);
    __builtin_amdgcn_s_setprio(1);
#pragma unroll
    for (int i = 0; i < 4; ++i)
#pragma unroll
      for (int j = 0; j < 6; ++j)
        acc[i][j] = __builtin_amdgcn_mfma_f32_16x16x32_bf16(af[i], bfq[j], acc[i][j], 0, 0, 0);
    __builtin_amdgcn_s_setprio(0);
    // ---- k-half 1: 24 MFMA ----
#pragma unroll
    for (int i = 0; i < 4; ++i) af[i]  = *(const bf16x8*)(bb + aRd[4 + i]);
#pragma unroll
    for (int j = 0; j < 6; ++j) bfq[j] = *(const bf16x8*)(bb + bRd[6 + j]);
    __builtin_amdgcn_s_setprio(1);
#pragma unroll
    for (int i = 0; i < 4; ++i)
#pragma unroll
      for (int j = 0; j < 6; ++j)
        acc[i][j] = __builtin_amdgcn_mfma_f32_16x16x32_bf16(af[i], bfq[j], acc[i][j], 0, 0, 0);
    __builtin_amdgcn_s_setprio(0);
  }

  // ---------- epilogue: 8 chunks of 16 tokens, coalesced f4 stores ----------
  // chunk buffer [c(3)][pr(4)][tk(16)][pw(16)] f32 = 12 KB in buf0; writer
  // spreads banks via pw ^ (lq<<2); reader undoes with lqw = tk>>2.
  const int b   = m0 >> 10;
  const int hl0 = (m0 & 1023) >> 5;
  float bv[6]; int cj[6], pwj[6], prj[6];
#pragma unroll
  for (int j = 0; j < 6; ++j) {
    int o = wn * 96 + j * 16 + lr;         // 0..191
    bv[j]  = bias[n0 + o];
    cj[j]  = o % 3;
    int oq = o / 3;
    pwj[j] = oq & 15;
    prj[j] = oq >> 4;                      // 0..3
  }
  float* ldsF = (float*)smem;

#pragma unroll
  for (int g = 0; g < 8; ++g) {
    if (wm == (g >> 2)) {
      const int i_f = g & 3;
#pragma unroll
      for (int j = 0; j < 6; ++j)
#pragma unroll
        for (int r = 0; r < 4; ++r) {
          const int tk = lq * 4 + r;
          ldsF[((cj[j] * 4 + prj[j]) << 8) + (tk << 4) + (pwj[j] ^ (lq << 2))] =
              acc[i_f][j][r] + bv[j];
        }
    }
    __syncthreads();
    const int hh = hl0 + (g >> 1);
#pragma unroll
    for (int u = 0; u < 3; ++u) {          // 768 f4, 256 thr -> 3 each
      const int f   = (u << 8) + tid;
      const int c   = f >> 8;              // == u
      const int pr  = (f >> 6) & 3;
      const int tk  = (f >> 2) & 15;
      const int pw0 = (f & 3) << 2;
      const int lqw = tk >> 2;
      float4 v = *(const float4*)(ldsF + (((c * 4 + pr) << 8) + (tk << 4)
                                          + (pw0 ^ (lqw << 2))));
      const size_t idx = (((size_t)(b * 3 + c)) << 18)
                       + (size_t)((hh << 4) + (nt << 2) + pr) * 512
                       + ((g & 1) << 8) + (tk << 4) + pw0;
      *(float4*)(out + idx) = v;
    }
    __syncthreads();
  }
}

// ===================== fallback: fused (no workspace) =====================
#define BM 64
#define BK 32
#define NTHR 1024
#define LDS_BYTES 53760

__global__ __launch_bounds__(NTHR, 4)
void fused_kernel(const float* __restrict__ x,
                  const float* __restrict__ lnw,
                  const float* __restrict__ lnb,
                  const float* __restrict__ Wf,
                  const float* __restrict__ bias,
                  float* __restrict__ out)
{
  extern __shared__ char smem[];
  char* AsBase = smem;
  char* BsBase = smem + 4096;
  float* smean = (float*)(smem + 53248);
  float* srstd = smean + BM;

  const int tid = threadIdx.x;
  const int m0  = blockIdx.x * BM;
  const int bb   = m0 >> 10;
  const int h0   = (m0 & 1023) >> 5;

  {
    const int row = tid >> 4;
    const int sub = tid & 15;
    const float4* xr = (const float4*)(x + (size_t)(m0 + row) * DDIM);
    float s = 0.f, ss = 0.f;
#pragma unroll 4
    for (int j = 0; j < 16; ++j) {
      float4 v = xr[sub + (j << 4)];
      s  += v.x + v.y + v.z + v.w;
      ss += v.x * v.x + v.y * v.y + v.z * v.z + v.w * v.w;
    }
#pragma unroll
    for (int off = 1; off < 16; off <<= 1) {
      s  += __shfl_xor(s, off);
      ss += __shfl_xor(ss, off);
    }
    if (sub == 0) {
      float mean = s * (1.f / 1024.f);
      float var  = ss * (1.f / 1024.f) - mean * mean;
      smean[row] = mean;
      srstd[row] = rsqrtf(var + LN_EPS);
    }
  }
  __syncthreads();

  const int arow  = tid >> 4;
  const int acol2 = tid & 15;
  const int aOff  = (m0 + arow) * DDIM + (acol2 << 1);
  const int aDst  = (arow << 6) + ((((acol2 >> 2) ^ ((arow >> 2) & 3)) << 4)) + ((acol2 & 3) << 2);
  const float aMean = smean[arow];
  const float aRstd = srstd[arow];

  int bOffF[6], bDstF[6];
#pragma unroll
  for (int c = 0; c < 6; ++c) {
    int idx = tid + (c << 10);
    int r = idx >> 3, c4 = idx & 7;
    bOffF[c] = r * DDIM + (c4 << 2);
    bDstF[c] = (r << 6) + ((((c4 >> 1) ^ ((r >> 2) & 3)) << 4)) + ((c4 & 1) << 3);
  }

  const int lane = tid & 63;
  const int wid  = tid >> 6;
  const int lr   = lane & 15;
  const int lq   = lane >> 4;
  const int kswz = (lq ^ ((lr >> 2) & 3)) << 4;
  int aRd[4], bRd[3];
#pragma unroll
  for (int i = 0; i < 4; ++i) aRd[i] = (((i << 4) + lr) << 6) + kswz;
#pragma unroll
  for (int j = 0; j < 3; ++j) bRd[j] = ((wid * 48 + (j << 4) + lr) << 6) + kswz;

  float2 aReg, lwReg, lbReg;
  float4 bRegF[6];

  auto loadTile = [&](int tt) {
    const int k0 = tt * BK;
    aReg  = *(const float2*)(x + aOff + k0);
    lwReg = *(const float2*)(lnw + (acol2 << 1) + k0);
    lbReg = *(const float2*)(lnb + (acol2 << 1) + k0);
#pragma unroll
    for (int c = 0; c < 6; ++c)
      bRegF[c] = *(const float4*)(Wf + bOffF[c] + k0);
  };

  auto storeTile = [&]() {
    float hx = (aReg.x - aMean) * aRstd * lwReg.x + lbReg.x;
    float hy = (aReg.y - aMean) * aRstd * lwReg.y + lbReg.y;
    hx = silu_f(hx); hy = silu_f(hy);
    ushort2 ap; ap.x = f2bf(hx); ap.y = f2bf(hy);
    *(ushort2*)(AsBase + aDst) = ap;
#pragma unroll
    for (int c = 0; c < 6; ++c) {
      float4 wv = bRegF[c];
      ushort4 bp; bp.x = f2bf(wv.x); bp.y = f2bf(wv.y); bp.z = f2bf(wv.z); bp.w = f2bf(wv.w);
      *(ushort4*)(BsBase + bDstF[c]) = bp;
    }
  };

  f32x4 acc[4][3];
#pragma unroll
  for (int i = 0; i < 4; ++i)
#pragma unroll
    for (int j = 0; j < 3; ++j)
      acc[i][j] = (f32x4){0.f, 0.f, 0.f, 0.f};

  loadTile(0);
  storeTile();
  __syncthreads();

  for (int t = 0; t < 32; ++t) {
    if (t < 31) loadTile(t + 1);
    bf16x8 af[4], bfr[3];
#pragma unroll
    for (int i = 0; i < 4; ++i) af[i] = *(const bf16x8*)(AsBase + aRd[i]);
#pragma unroll
    for (int j = 0; j < 3; ++j) bfr[j] = *(const bf16x8*)(BsBase + bRd[j]);
#pragma unroll
    for (int i = 0; i < 4; ++i)
#pragma unroll
      for (int j = 0; j < 3; ++j)
        acc[i][j] = __builtin_amdgcn_mfma_f32_16x16x32_bf16(af[i], bfr[j], acc[i][j], 0, 0, 0);
    __syncthreads();
    if (t < 31) storeTile();
    __syncthreads();
  }

  float* ldsF = (float*)smem;
  float bv[3]; int cv[3], phv[3], pwv[3];
#pragma unroll
  for (int j = 0; j < 3; ++j) {
    const int o = wid * 48 + (j << 4) + lr;
    bv[j]  = bias[o];
    cv[j]  = o % 3;
    const int oq = o / 3;
    pwv[j] = oq & 15;
    phv[j] = oq >> 4;
  }

#pragma unroll
  for (int i = 0; i < 4; ++i) {
#pragma unroll
    for (int j = 0; j < 3; ++j) {
#pragma unroll
      for (int r = 0; r < 4; ++r) {
        const int wl  = (lq << 2) + r;
        const int lin = ((cv[j] * 16 + phv[j]) << 8) + (wl << 4) + pwv[j];
        const int dws = lin ^ (cv[j] << 2) ^ (((lin >> 6) & 1) << 4);
        ldsF[dws] = acc[i][j][r] + bv[j];
      }
    }
    __syncthreads();
    const int hq = h0 + (i >> 1);
    const int w0 = (i & 1) << 4;
#pragma unroll
    for (int q = 0; q < 3; ++q) {
      const int g4  = (q << 10) + tid;
      const int dw  = g4 << 2;
      const int run = dw >> 8;
      const int c   = run >> 4;
      const int ph  = run & 15;
      const int wl  = (dw >> 4) & 15;
      const int pw  = dw & 15;
      const int dws = dw ^ (c << 2) ^ (((dw >> 6) & 1) << 4);
      float4 v = *(const float4*)(ldsF + dws);
      const size_t idx = (((size_t)(bb * 3 + c)) << 18)
                       + ((size_t)((hq << 4) + ph) << 9)
                       + ((w0 + wl) << 4) + pw;
      *(float4*)(out + idx) = v;
    }
    __syncthreads();
  }
}

extern "C" void kernel_launch(void* const* d_in, const int* in_sizes, int n_in,
                              void* d_out, int out_size, void* d_ws, size_t ws_size,
                              hipStream_t stream) {
  const float* x    = (const float*)d_in[0];
  const float* lnw  = (const float*)d_in[1];
  const float* lnb  = (const float*)d_in[2];
  const float* W    = (const float*)d_in[3];
  const float* bias = (const float*)d_in[4];
  float* out = (float*)d_out;

  const size_t wbBytes = (size_t)ODIM * DDIM * sizeof(__hip_bfloat16);   // 1.5 MB
  const size_t hBytes  = (size_t)M_TOT * DDIM * sizeof(__hip_bfloat16);  // 64 MB
  __hip_bfloat16* Wb = (__hip_bfloat16*)d_ws;
  __hip_bfloat16* hb = (__hip_bfloat16*)((char*)d_ws + wbBytes);

  if (ws_size >= wbBytes + hBytes) {
    wconv_kernel<<<dim3(768), dim3(256), 0, stream>>>((const float4*)W, (ushort4*)Wb,
                                                      ODIM * DDIM / 4);
    ln_silu_kernel<<<dim3(M_TOT / 4), dim3(256), 0, stream>>>(x, lnw, lnb, hb);
    gemm_kernel<<<dim3((M_TOT / GBM) * (ODIM / GBN)), dim3(256), 0, stream>>>(hb, Wb, bias, out);
  } else {
    fused_kernel<<<dim3(M_TOT / BM), dim3(NTHR), LDS_BYTES, stream>>>(
        x, lnw, lnb, W, bias, out);
  }
}